// Round 15
// baseline (167.304 us; speedup 1.0000x reference)
//
#include <hip/hip_runtime.h>

#define N_NODES 100000
#define N_EDGES 1600000
#define NBKT 391          // buckets = ceil(100000/256)
#define BKT_SLACK 5120    // per-bucket capacity (mean 4096, sd 64 -> +16 sd)
#define EPB 8192          // edges per binA block (R15: 4096->8192, longer runs)
#define BINA_BLOCKS ((N_EDGES + EPB - 1) / EPB)   // 196

typedef __attribute__((ext_vector_type(8))) short short8;
typedef __attribute__((ext_vector_type(4))) float f32x4;

__device__ __forceinline__ unsigned short f2bf(float f) {
    unsigned u = __float_as_uint(f);
    u = u + 0x7fffu + ((u >> 16) & 1u);       // RNE
    return (unsigned short)(u >> 16);
}
__device__ __forceinline__ float bf2f(unsigned short h) {
    return __uint_as_float((unsigned)h << 16);
}

// ---------------------------------------------------------------------------
// proj (MFMA): h = x @ W^T via split-bf16 (xh+xl)(Wh+Wl), drop xl*Wl.
// 32-row tiles, W fragments in registers, inline hi/lo convert (R13-verified
// best).  Block 0 zeroes gcur (proj precedes binA in stream order).
// ---------------------------------------------------------------------------
__global__ __launch_bounds__(256) void proj_kernel(
    const float* __restrict__ x, const float* __restrict__ W,
    const float* __restrict__ a_src, const float* __restrict__ a_dst,
    unsigned short* __restrict__ hout, float* __restrict__ s_src,
    float* __restrict__ s_dst, int* __restrict__ gcur)
{
    __shared__ char smem[16384];
    char* xh = smem;                 // 8 KB  (32 rows x 256B)
    char* xl = smem + 8192;          // 8 KB
    const int t = threadIdx.x;
    const int br = blockIdx.x * 32;
    const int wave = t >> 6, lane = t & 63;
    const int lr = lane & 15, q = lane >> 4;

    if (blockIdx.x == 0) {            // fold gcur zeroing into this kernel
        ((int*)gcur)[t] = 0;
        ((int*)gcur)[256 + t] = 0;
    }

    // W fragments -> registers (hi/lo split inline); lane l holds
    // W[wave*32+ct*16+(l&15)][(ks*4+(l>>4))*8 ..+8]
    short8 wh[2][4], wl[2][4];
#pragma unroll
    for (int ct = 0; ct < 2; ++ct) {
#pragma unroll
        for (int ks = 0; ks < 4; ++ks) {
            int o = wave * 32 + ct * 16 + lr;
            int k0 = (ks * 4 + q) * 8;
            float4 v0 = *(const float4*)&W[o * 128 + k0];
            float4 v1 = *(const float4*)&W[o * 128 + k0 + 4];
            float vv[8] = {v0.x, v0.y, v0.z, v0.w, v1.x, v1.y, v1.z, v1.w};
            short8 h8, l8;
#pragma unroll
            for (int j = 0; j < 8; ++j) {
                unsigned short hi = f2bf(vv[j]);
                h8[j] = (short)hi;
                l8[j] = (short)f2bf(vv[j] - bf2f(hi));
            }
            wh[ct][ks] = h8;
            wl[ct][ks] = l8;
        }
    }

    // stage x with on-the-fly hi/lo split (swizzled 16B granules)
    {
        int row = t >> 3;
        size_t gb = (size_t)(br + row) * 128;
#pragma unroll
        for (int i = 0; i < 4; ++i) {
            int k = ((t & 7) * 4 + i) * 4;
            float4 v = *(const float4*)&x[gb + k];
            ushort4 hi, lo;
            hi.x = f2bf(v.x); lo.x = f2bf(v.x - bf2f(hi.x));
            hi.y = f2bf(v.y); lo.y = f2bf(v.y - bf2f(hi.y));
            hi.z = f2bf(v.z); lo.z = f2bf(v.z - bf2f(hi.z));
            hi.w = f2bf(v.w); lo.w = f2bf(v.w - bf2f(hi.w));
            int byt = row * 256 + (((k >> 3) ^ (row & 7)) * 16) + (k & 7) * 2;
            *(ushort4*)(xh + byt) = hi;
            *(ushort4*)(xl + byt) = lo;
        }
    }
    __syncthreads();

    f32x4 acc[2][2] = {};

#pragma unroll
    for (int ks = 0; ks < 4; ++ks) {
        int sl = ((ks * 4 + q) ^ (lr & 7)) * 16;
        int a0o = lr * 256 + sl, a1o = (16 + lr) * 256 + sl;
        short8 ah0 = *(const short8*)(xh + a0o);
        short8 ah1 = *(const short8*)(xh + a1o);
        short8 al0 = *(const short8*)(xl + a0o);
        short8 al1 = *(const short8*)(xl + a1o);
        acc[0][0] = __builtin_amdgcn_mfma_f32_16x16x32_bf16(ah0, wh[0][ks], acc[0][0], 0, 0, 0);
        acc[0][1] = __builtin_amdgcn_mfma_f32_16x16x32_bf16(ah0, wh[1][ks], acc[0][1], 0, 0, 0);
        acc[1][0] = __builtin_amdgcn_mfma_f32_16x16x32_bf16(ah1, wh[0][ks], acc[1][0], 0, 0, 0);
        acc[1][1] = __builtin_amdgcn_mfma_f32_16x16x32_bf16(ah1, wh[1][ks], acc[1][1], 0, 0, 0);
        acc[0][0] = __builtin_amdgcn_mfma_f32_16x16x32_bf16(al0, wh[0][ks], acc[0][0], 0, 0, 0);
        acc[0][1] = __builtin_amdgcn_mfma_f32_16x16x32_bf16(al0, wh[1][ks], acc[0][1], 0, 0, 0);
        acc[1][0] = __builtin_amdgcn_mfma_f32_16x16x32_bf16(al1, wh[0][ks], acc[1][0], 0, 0, 0);
        acc[1][1] = __builtin_amdgcn_mfma_f32_16x16x32_bf16(al1, wh[1][ks], acc[1][1], 0, 0, 0);
        acc[0][0] = __builtin_amdgcn_mfma_f32_16x16x32_bf16(ah0, wl[0][ks], acc[0][0], 0, 0, 0);
        acc[0][1] = __builtin_amdgcn_mfma_f32_16x16x32_bf16(ah0, wl[1][ks], acc[0][1], 0, 0, 0);
        acc[1][0] = __builtin_amdgcn_mfma_f32_16x16x32_bf16(ah1, wl[0][ks], acc[1][0], 0, 0, 0);
        acc[1][1] = __builtin_amdgcn_mfma_f32_16x16x32_bf16(ah1, wl[1][ks], acc[1][1], 0, 0, 0);
    }

    // s_src/s_dst epilogue: C/D layout col=lane&15, row=q*4+reg
    float as0 = a_src[wave * 32 + lr], as1 = a_src[wave * 32 + 16 + lr];
    float ad0 = a_dst[wave * 32 + lr], ad1 = a_dst[wave * 32 + 16 + lr];
#pragma unroll
    for (int r = 0; r < 2; ++r) {
#pragma unroll
        for (int reg = 0; reg < 4; ++reg) {
            float ps = acc[r][0][reg] * as0 + acc[r][1][reg] * as1;
            float pd = acc[r][0][reg] * ad0 + acc[r][1][reg] * ad1;
            ps += __shfl_xor(ps, 1); ps += __shfl_xor(ps, 2);
            ps += __shfl_xor(ps, 4); ps += __shfl_xor(ps, 8);
            pd += __shfl_xor(pd, 1); pd += __shfl_xor(pd, 2);
            pd += __shfl_xor(pd, 4); pd += __shfl_xor(pd, 8);
            if (lr == 0) {
                int grow = br + r * 16 + q * 4 + reg;
                s_src[grow * 4 + wave] = ps;
                s_dst[grow * 4 + wave] = pd;
            }
        }
    }

    // h: transpose through LDS (reuse x region) -> coalesced bf16 stores
    __syncthreads();
    unsigned short* hl = (unsigned short*)smem;   // [32][128] = 8 KB
#pragma unroll
    for (int r = 0; r < 2; ++r)
#pragma unroll
        for (int c = 0; c < 2; ++c)
#pragma unroll
            for (int reg = 0; reg < 4; ++reg)
                hl[(r * 16 + q * 4 + reg) * 128 + wave * 32 + c * 16 + lr] =
                    f2bf(acc[r][c][reg]);
    __syncthreads();
    {
        int row = t >> 3, cb = (t & 7) * 16;
        uint4 v0 = *(uint4*)&hl[row * 128 + cb];
        uint4 v1 = *(uint4*)&hl[row * 128 + cb + 8];
        *(uint4*)&hout[(size_t)(br + row) * 128 + cb] = v0;
        *(uint4*)&hout[(size_t)(br + row) * 128 + cb + 8] = v1;
    }
}

// ---------------------------------------------------------------------------
// binA: bucket edges by dst>>8.  EPB=8192: runs of ~21 records (~168B) per
// (block,bucket) -> lower 64B-line write amplification, half the
// reservation atomics.
// ---------------------------------------------------------------------------
__global__ __launch_bounds__(256) void binA_kernel(
    const int* __restrict__ ei, const float* __restrict__ ew,
    int* __restrict__ gcur, uint2* __restrict__ ebin)
{
    __shared__ int hist[NBKT];
    __shared__ int runbase[NBKT];
    const int t = threadIdx.x;
    const int base = blockIdx.x * EPB;
    for (int b = t; b < NBKT; b += 256) hist[b] = 0;
    __syncthreads();
#pragma unroll
    for (int i = 0; i < EPB / 256; ++i) {
        int e = base + i * 256 + t;
        if (e < N_EDGES) atomicAdd(&hist[ei[N_EDGES + e] >> 8], 1);
    }
    __syncthreads();
    for (int b = t; b < NBKT; b += 256) {
        int c = hist[b];
        runbase[b] = (c > 0) ? atomicAdd(&gcur[b], c) : 0;
        hist[b] = 0;                       // reuse as local cursor
    }
    __syncthreads();
#pragma unroll
    for (int i = 0; i < EPB / 256; ++i) {
        int e = base + i * 256 + t;
        if (e >= N_EDGES) continue;
        int s = ei[e];
        int d = ei[N_EDGES + e];
        int b = d >> 8;
        int lpos = atomicAdd(&hist[b], 1);
        ebin[(size_t)b * BKT_SLACK + runbase[b] + lpos] =
            make_uint2((unsigned)s | ((unsigned)(d & 255) << 17),
                       __float_as_uint(ew[e]));
    }
}

// ---------------------------------------------------------------------------
// binB: one block per bucket; inline prefix over gcur; rowp/deg; CSR scatter
// ---------------------------------------------------------------------------
__global__ __launch_bounds__(256) void binB_kernel(
    const uint2* __restrict__ ebin, const int* __restrict__ gcur,
    uint2* __restrict__ earr, int* __restrict__ rowp, int* __restrict__ deg)
{
    __shared__ int cnt[256];
    __shared__ int sc[256];
    __shared__ int cur[256];
    const int b = blockIdx.x;
    const int t = threadIdx.x;
    int acc = 0;
    for (int i = t; i < b; i += 256) acc += gcur[i];
    sc[t] = acc; __syncthreads();
    for (int off = 1; off < 256; off <<= 1) {
        int a = sc[t];
        int bb = (t >= off) ? sc[t - off] : 0;
        __syncthreads();
        sc[t] = a + bb;
        __syncthreads();
    }
    const int base = sc[255];
    __syncthreads();
    cnt[t] = 0;
    __syncthreads();
    const int count = gcur[b];
    const uint2* bp = ebin + (size_t)b * BKT_SLACK;
    for (int i = t; i < count; i += 256)
        atomicAdd(&cnt[(bp[i].x >> 17) & 255], 1);
    __syncthreads();
    int c = cnt[t];
    sc[t] = c; __syncthreads();
    for (int off = 1; off < 256; off <<= 1) {
        int a = sc[t];
        int bb = (t >= off) ? sc[t - off] : 0;
        __syncthreads();
        sc[t] = a + bb;
        __syncthreads();
    }
    int excl = sc[t] - c;
    int node = b * 256 + t;
    if (node < N_NODES) { rowp[node] = base + excl; deg[node] = c; }
    cur[t] = base + excl;
    __syncthreads();
    for (int i = t; i < count; i += 256) {
        uint2 rec = bp[i];
        int pos = atomicAdd(&cur[(rec.x >> 17) & 255], 1);
        earr[pos] = make_uint2(rec.x & 0x1FFFFu, rec.y);
    }
}

// ---------------------------------------------------------------------------
// Gather: 16 lanes per node; branch-free fully-unrolled 16-edge batches
// (R11-verified; at the Infinity-Cache random-256B BW ceiling ~3.7 TB/s)
// ---------------------------------------------------------------------------
__global__ __launch_bounds__(256) void gather_kernel(
    const uint2* __restrict__ earr, const int* __restrict__ rowp,
    const int* __restrict__ deg, const float* __restrict__ s_src,
    const float* __restrict__ s_dst,
    const unsigned short* __restrict__ hbuf, float* __restrict__ out)
{
    __shared__ float lds_alpha[16][17][4];
    __shared__ int lds_src[16][17];
    const int ln = threadIdx.x >> 4;          // node slot 0..15
    const int sub = threadIdx.x & 15;
    const int n = blockIdx.x * 16 + ln;       // grid exact: 6250 blocks
    const int start = rowp[n];
    const int dg = deg[n];
    const float4 sd = *(const float4*)&s_dst[n * 4];
    const int hd3 = sub >> 2;                 // head of this lane's 8 channels

    float ps0 = 0.f, ps1 = 0.f, ps2 = 0.f, ps3 = 0.f;
    float ac0 = 0.f, ac1 = 0.f, ac2 = 0.f, ac3 = 0.f;
    float ac4 = 0.f, ac5 = 0.f, ac6 = 0.f, ac7 = 0.f;

    for (int b0 = 0; b0 < dg; b0 += 16) {
        int nb = dg - b0; if (nb > 16) nb = 16;
        float a0 = 0.f, a1 = 0.f, a2 = 0.f, a3 = 0.f;
        int sid = 0;
        if (sub < nb) {
            uint2 rec = earr[start + b0 + sub];
            sid = (int)rec.x;
            float wgt = __uint_as_float(rec.y);
            float4 ss = *(const float4*)&s_src[sid * 4];
            float v;
            v = ss.x + sd.x; v = (v > 0.f ? v : 0.2f * v) * wgt; a0 = __expf(v);
            v = ss.y + sd.y; v = (v > 0.f ? v : 0.2f * v) * wgt; a1 = __expf(v);
            v = ss.z + sd.z; v = (v > 0.f ? v : 0.2f * v) * wgt; a2 = __expf(v);
            v = ss.w + sd.w; v = (v > 0.f ? v : 0.2f * v) * wgt; a3 = __expf(v);
            ps0 += a0; ps1 += a1; ps2 += a2; ps3 += a3;
        }
        *(float4*)&lds_alpha[ln][sub][0] = make_float4(a0, a1, a2, a3);
        lds_src[ln][sub] = sid;

        float co[16];
        uint4 hv[16];
#pragma unroll
        for (int e = 0; e < 16; ++e) {
            co[e] = lds_alpha[ln][e][hd3];
            int s = lds_src[ln][e];
            hv[e] = *(const uint4*)&hbuf[(size_t)s * 128 + sub * 8];
        }
#pragma unroll
        for (int e = 0; e < 16; ++e) {
            ac0 = fmaf(co[e], __uint_as_float(hv[e].x << 16), ac0);
            ac1 = fmaf(co[e], __uint_as_float(hv[e].x & 0xffff0000u), ac1);
            ac2 = fmaf(co[e], __uint_as_float(hv[e].y << 16), ac2);
            ac3 = fmaf(co[e], __uint_as_float(hv[e].y & 0xffff0000u), ac3);
            ac4 = fmaf(co[e], __uint_as_float(hv[e].z << 16), ac4);
            ac5 = fmaf(co[e], __uint_as_float(hv[e].z & 0xffff0000u), ac5);
            ac6 = fmaf(co[e], __uint_as_float(hv[e].w << 16), ac6);
            ac7 = fmaf(co[e], __uint_as_float(hv[e].w & 0xffff0000u), ac7);
        }
    }
#pragma unroll
    for (int off = 1; off < 16; off <<= 1) {
        ps0 += __shfl_xor(ps0, off);
        ps1 += __shfl_xor(ps1, off);
        ps2 += __shfl_xor(ps2, off);
        ps3 += __shfl_xor(ps3, off);
    }
    float sv = (hd3 & 2) ? ((hd3 & 1) ? ps3 : ps2) : ((hd3 & 1) ? ps1 : ps0);
    float inv = 1.f / (sv + 1e-8f);
    float4 o0 = {ac0 * inv, ac1 * inv, ac2 * inv, ac3 * inv};
    float4 o1 = {ac4 * inv, ac5 * inv, ac6 * inv, ac7 * inv};
    *(float4*)&out[(size_t)n * 128 + sub * 8] = o0;
    *(float4*)&out[(size_t)n * 128 + sub * 8 + 4] = o1;
}

extern "C" void kernel_launch(void* const* d_in, const int* in_sizes, int n_in,
                              void* d_out, int out_size, void* d_ws, size_t ws_size,
                              hipStream_t stream)
{
    const float* x     = (const float*)d_in[0];
    const int*   ei    = (const int*)d_in[1];
    const float* ew    = (const float*)d_in[2];
    const float* W     = (const float*)d_in[3];
    const float* a_src = (const float*)d_in[4];
    const float* a_dst = (const float*)d_in[5];
    float* out = (float*)d_out;
    char* ws = (char*)d_ws;

    // workspace layout (byte offsets)
    unsigned short* hbuf = (unsigned short*)(ws);           // 25.6 MB bf16
    float* s_src = (float*)(ws + 25600000);                 // 1.6 MB
    float* s_dst = (float*)(ws + 27200000);                 // 1.6 MB
    int*   deg   = (int*)(ws + 28800000);                   // 400 KB
    int*   rowp  = (int*)(ws + 29200000);                   // 400 KB
    int*   gcur  = (int*)(ws + 29600000);                   // 2 KB (391 used)
    uint2* earr  = (uint2*)(ws + 29669632);                 // 12.8 MB
    uint2* ebin  = (uint2*)(ws + 42469632);                 // 16.0 MB

    proj_kernel<<<N_NODES / 32, 256, 0, stream>>>(x, W, a_src, a_dst,
                                                  hbuf, s_src, s_dst, gcur);
    binA_kernel<<<BINA_BLOCKS, 256, 0, stream>>>(ei, ew, gcur, ebin);
    binB_kernel<<<NBKT, 256, 0, stream>>>(ebin, gcur, earr, rowp, deg);
    gather_kernel<<<N_NODES / 16, 256, 0, stream>>>(earr, rowp, deg, s_src, s_dst,
                                                    hbuf, out);
}

// Round 17
// 161.486 us; speedup vs baseline: 1.0360x; 1.0360x over previous
//
#include <hip/hip_runtime.h>

#define N_NODES 100000
#define N_EDGES 1600000
#define NBKT 391          // buckets = ceil(100000/256)
#define BKT_SLACK 5120    // per-bucket capacity (mean 4096, sd 64 -> +16 sd)
#define EPB 4096          // edges per binA block
#define BINA_BLOCKS ((N_EDGES + EPB - 1) / EPB)   // 391

typedef __attribute__((ext_vector_type(8))) short short8;
typedef __attribute__((ext_vector_type(4))) float f32x4;

__device__ __forceinline__ unsigned short f2bf(float f) {
    unsigned u = __float_as_uint(f);
    u = u + 0x7fffu + ((u >> 16) & 1u);       // RNE
    return (unsigned short)(u >> 16);
}
__device__ __forceinline__ float bf2f(unsigned short h) {
    return __uint_as_float((unsigned)h << 16);
}

// ---------------------------------------------------------------------------
// proj (MFMA): h = x @ W^T via split-bf16 (xh+xl)(Wh+Wl), drop xl*Wl.
// 32-row tiles, W fragments in registers, inline hi/lo convert (R13-verified
// best).  Block 0 zeroes gcur (proj precedes binA in stream order).
// ---------------------------------------------------------------------------
__global__ __launch_bounds__(256) void proj_kernel(
    const float* __restrict__ x, const float* __restrict__ W,
    const float* __restrict__ a_src, const float* __restrict__ a_dst,
    unsigned short* __restrict__ hout, float* __restrict__ s_src,
    float* __restrict__ s_dst, int* __restrict__ gcur)
{
    __shared__ char smem[16384];
    char* xh = smem;                 // 8 KB  (32 rows x 256B)
    char* xl = smem + 8192;          // 8 KB
    const int t = threadIdx.x;
    const int br = blockIdx.x * 32;
    const int wave = t >> 6, lane = t & 63;
    const int lr = lane & 15, q = lane >> 4;

    if (blockIdx.x == 0) {            // fold gcur zeroing into this kernel
        ((int*)gcur)[t] = 0;
        ((int*)gcur)[256 + t] = 0;
    }

    // W fragments -> registers (hi/lo split inline); lane l holds
    // W[wave*32+ct*16+(l&15)][(ks*4+(l>>4))*8 ..+8]
    short8 wh[2][4], wl[2][4];
#pragma unroll
    for (int ct = 0; ct < 2; ++ct) {
#pragma unroll
        for (int ks = 0; ks < 4; ++ks) {
            int o = wave * 32 + ct * 16 + lr;
            int k0 = (ks * 4 + q) * 8;
            float4 v0 = *(const float4*)&W[o * 128 + k0];
            float4 v1 = *(const float4*)&W[o * 128 + k0 + 4];
            float vv[8] = {v0.x, v0.y, v0.z, v0.w, v1.x, v1.y, v1.z, v1.w};
            short8 h8, l8;
#pragma unroll
            for (int j = 0; j < 8; ++j) {
                unsigned short hi = f2bf(vv[j]);
                h8[j] = (short)hi;
                l8[j] = (short)f2bf(vv[j] - bf2f(hi));
            }
            wh[ct][ks] = h8;
            wl[ct][ks] = l8;
        }
    }

    // stage x with on-the-fly hi/lo split (swizzled 16B granules)
    {
        int row = t >> 3;
        size_t gb = (size_t)(br + row) * 128;
#pragma unroll
        for (int i = 0; i < 4; ++i) {
            int k = ((t & 7) * 4 + i) * 4;
            float4 v = *(const float4*)&x[gb + k];
            ushort4 hi, lo;
            hi.x = f2bf(v.x); lo.x = f2bf(v.x - bf2f(hi.x));
            hi.y = f2bf(v.y); lo.y = f2bf(v.y - bf2f(hi.y));
            hi.z = f2bf(v.z); lo.z = f2bf(v.z - bf2f(hi.z));
            hi.w = f2bf(v.w); lo.w = f2bf(v.w - bf2f(hi.w));
            int byt = row * 256 + (((k >> 3) ^ (row & 7)) * 16) + (k & 7) * 2;
            *(ushort4*)(xh + byt) = hi;
            *(ushort4*)(xl + byt) = lo;
        }
    }
    __syncthreads();

    f32x4 acc[2][2] = {};

#pragma unroll
    for (int ks = 0; ks < 4; ++ks) {
        int sl = ((ks * 4 + q) ^ (lr & 7)) * 16;
        int a0o = lr * 256 + sl, a1o = (16 + lr) * 256 + sl;
        short8 ah0 = *(const short8*)(xh + a0o);
        short8 ah1 = *(const short8*)(xh + a1o);
        short8 al0 = *(const short8*)(xl + a0o);
        short8 al1 = *(const short8*)(xl + a1o);
        acc[0][0] = __builtin_amdgcn_mfma_f32_16x16x32_bf16(ah0, wh[0][ks], acc[0][0], 0, 0, 0);
        acc[0][1] = __builtin_amdgcn_mfma_f32_16x16x32_bf16(ah0, wh[1][ks], acc[0][1], 0, 0, 0);
        acc[1][0] = __builtin_amdgcn_mfma_f32_16x16x32_bf16(ah1, wh[0][ks], acc[1][0], 0, 0, 0);
        acc[1][1] = __builtin_amdgcn_mfma_f32_16x16x32_bf16(ah1, wh[1][ks], acc[1][1], 0, 0, 0);
        acc[0][0] = __builtin_amdgcn_mfma_f32_16x16x32_bf16(al0, wh[0][ks], acc[0][0], 0, 0, 0);
        acc[0][1] = __builtin_amdgcn_mfma_f32_16x16x32_bf16(al0, wh[1][ks], acc[0][1], 0, 0, 0);
        acc[1][0] = __builtin_amdgcn_mfma_f32_16x16x32_bf16(al1, wh[0][ks], acc[1][0], 0, 0, 0);
        acc[1][1] = __builtin_amdgcn_mfma_f32_16x16x32_bf16(al1, wh[1][ks], acc[1][1], 0, 0, 0);
        acc[0][0] = __builtin_amdgcn_mfma_f32_16x16x32_bf16(ah0, wl[0][ks], acc[0][0], 0, 0, 0);
        acc[0][1] = __builtin_amdgcn_mfma_f32_16x16x32_bf16(ah0, wl[1][ks], acc[0][1], 0, 0, 0);
        acc[1][0] = __builtin_amdgcn_mfma_f32_16x16x32_bf16(ah1, wl[0][ks], acc[1][0], 0, 0, 0);
        acc[1][1] = __builtin_amdgcn_mfma_f32_16x16x32_bf16(ah1, wl[1][ks], acc[1][1], 0, 0, 0);
    }

    // s_src/s_dst epilogue: C/D layout col=lane&15, row=q*4+reg
    float as0 = a_src[wave * 32 + lr], as1 = a_src[wave * 32 + 16 + lr];
    float ad0 = a_dst[wave * 32 + lr], ad1 = a_dst[wave * 32 + 16 + lr];
#pragma unroll
    for (int r = 0; r < 2; ++r) {
#pragma unroll
        for (int reg = 0; reg < 4; ++reg) {
            float ps = acc[r][0][reg] * as0 + acc[r][1][reg] * as1;
            float pd = acc[r][0][reg] * ad0 + acc[r][1][reg] * ad1;
            ps += __shfl_xor(ps, 1); ps += __shfl_xor(ps, 2);
            ps += __shfl_xor(ps, 4); ps += __shfl_xor(ps, 8);
            pd += __shfl_xor(pd, 1); pd += __shfl_xor(pd, 2);
            pd += __shfl_xor(pd, 4); pd += __shfl_xor(pd, 8);
            if (lr == 0) {
                int grow = br + r * 16 + q * 4 + reg;
                s_src[grow * 4 + wave] = ps;
                s_dst[grow * 4 + wave] = pd;
            }
        }
    }

    // h: transpose through LDS (reuse x region) -> coalesced bf16 stores
    __syncthreads();
    unsigned short* hl = (unsigned short*)smem;   // [32][128] = 8 KB
#pragma unroll
    for (int r = 0; r < 2; ++r)
#pragma unroll
        for (int c = 0; c < 2; ++c)
#pragma unroll
            for (int reg = 0; reg < 4; ++reg)
                hl[(r * 16 + q * 4 + reg) * 128 + wave * 32 + c * 16 + lr] =
                    f2bf(acc[r][c][reg]);
    __syncthreads();
    {
        int row = t >> 3, cb = (t & 7) * 16;
        uint4 v0 = *(uint4*)&hl[row * 128 + cb];
        uint4 v1 = *(uint4*)&hl[row * 128 + cb + 8];
        *(uint4*)&hout[(size_t)(br + row) * 128 + cb] = v0;
        *(uint4*)&hout[(size_t)(br + row) * 128 + cb + 8] = v1;
    }
}

// ---------------------------------------------------------------------------
// binA: bucket edges by dst>>8 (R13-verified, EPB=4096)
// ---------------------------------------------------------------------------
__global__ __launch_bounds__(256) void binA_kernel(
    const int* __restrict__ ei, const float* __restrict__ ew,
    int* __restrict__ gcur, uint2* __restrict__ ebin)
{
    __shared__ int hist[NBKT];
    __shared__ int runbase[NBKT];
    const int t = threadIdx.x;
    const int base = blockIdx.x * EPB;
    for (int b = t; b < NBKT; b += 256) hist[b] = 0;
    __syncthreads();
#pragma unroll
    for (int i = 0; i < EPB / 256; ++i) {
        int e = base + i * 256 + t;
        if (e < N_EDGES) atomicAdd(&hist[ei[N_EDGES + e] >> 8], 1);
    }
    __syncthreads();
    for (int b = t; b < NBKT; b += 256) {
        int c = hist[b];
        runbase[b] = (c > 0) ? atomicAdd(&gcur[b], c) : 0;
        hist[b] = 0;                       // reuse as local cursor
    }
    __syncthreads();
#pragma unroll
    for (int i = 0; i < EPB / 256; ++i) {
        int e = base + i * 256 + t;
        if (e >= N_EDGES) continue;
        int s = ei[e];
        int d = ei[N_EDGES + e];
        int b = d >> 8;
        int lpos = atomicAdd(&hist[b], 1);
        ebin[(size_t)b * BKT_SLACK + runbase[b] + lpos] =
            make_uint2((unsigned)s | ((unsigned)(d & 255) << 17),
                       __float_as_uint(ew[e]));
    }
}

// ---------------------------------------------------------------------------
// binB: one block per bucket; inline prefix over gcur; rowp/deg; CSR scatter
// (exact R13 version — R16's uint4 variant caused a replay divergence)
// ---------------------------------------------------------------------------
__global__ __launch_bounds__(256) void binB_kernel(
    const uint2* __restrict__ ebin, const int* __restrict__ gcur,
    uint2* __restrict__ earr, int* __restrict__ rowp, int* __restrict__ deg)
{
    __shared__ int cnt[256];
    __shared__ int sc[256];
    __shared__ int cur[256];
    const int b = blockIdx.x;
    const int t = threadIdx.x;
    int acc = 0;
    for (int i = t; i < b; i += 256) acc += gcur[i];
    sc[t] = acc; __syncthreads();
    for (int off = 1; off < 256; off <<= 1) {
        int a = sc[t];
        int bb = (t >= off) ? sc[t - off] : 0;
        __syncthreads();
        sc[t] = a + bb;
        __syncthreads();
    }
    const int base = sc[255];
    __syncthreads();
    cnt[t] = 0;
    __syncthreads();
    const int count = gcur[b];
    const uint2* bp = ebin + (size_t)b * BKT_SLACK;
    for (int i = t; i < count; i += 256)
        atomicAdd(&cnt[(bp[i].x >> 17) & 255], 1);
    __syncthreads();
    int c = cnt[t];
    sc[t] = c; __syncthreads();
    for (int off = 1; off < 256; off <<= 1) {
        int a = sc[t];
        int bb = (t >= off) ? sc[t - off] : 0;
        __syncthreads();
        sc[t] = a + bb;
        __syncthreads();
    }
    int excl = sc[t] - c;
    int node = b * 256 + t;
    if (node < N_NODES) { rowp[node] = base + excl; deg[node] = c; }
    cur[t] = base + excl;
    __syncthreads();
    for (int i = t; i < count; i += 256) {
        uint2 rec = bp[i];
        int pos = atomicAdd(&cur[(rec.x >> 17) & 255], 1);
        earr[pos] = make_uint2(rec.x & 0x1FFFFu, rec.y);
    }
}

// ---------------------------------------------------------------------------
// Gather: 16 lanes per node; branch-free fully-unrolled 16-edge batches
// (R11-verified; at the random-256B L2-miss/L3 path ceiling, 5 structures
// all land at 75.7 +/- 0.3 us)
// ---------------------------------------------------------------------------
__global__ __launch_bounds__(256) void gather_kernel(
    const uint2* __restrict__ earr, const int* __restrict__ rowp,
    const int* __restrict__ deg, const float* __restrict__ s_src,
    const float* __restrict__ s_dst,
    const unsigned short* __restrict__ hbuf, float* __restrict__ out)
{
    __shared__ float lds_alpha[16][17][4];
    __shared__ int lds_src[16][17];
    const int ln = threadIdx.x >> 4;          // node slot 0..15
    const int sub = threadIdx.x & 15;
    const int n = blockIdx.x * 16 + ln;       // grid exact: 6250 blocks
    const int start = rowp[n];
    const int dg = deg[n];
    const float4 sd = *(const float4*)&s_dst[n * 4];
    const int hd3 = sub >> 2;                 // head of this lane's 8 channels

    float ps0 = 0.f, ps1 = 0.f, ps2 = 0.f, ps3 = 0.f;
    float ac0 = 0.f, ac1 = 0.f, ac2 = 0.f, ac3 = 0.f;
    float ac4 = 0.f, ac5 = 0.f, ac6 = 0.f, ac7 = 0.f;

    for (int b0 = 0; b0 < dg; b0 += 16) {
        int nb = dg - b0; if (nb > 16) nb = 16;
        float a0 = 0.f, a1 = 0.f, a2 = 0.f, a3 = 0.f;
        int sid = 0;
        if (sub < nb) {
            uint2 rec = earr[start + b0 + sub];
            sid = (int)rec.x;
            float wgt = __uint_as_float(rec.y);
            float4 ss = *(const float4*)&s_src[sid * 4];
            float v;
            v = ss.x + sd.x; v = (v > 0.f ? v : 0.2f * v) * wgt; a0 = __expf(v);
            v = ss.y + sd.y; v = (v > 0.f ? v : 0.2f * v) * wgt; a1 = __expf(v);
            v = ss.z + sd.z; v = (v > 0.f ? v : 0.2f * v) * wgt; a2 = __expf(v);
            v = ss.w + sd.w; v = (v > 0.f ? v : 0.2f * v) * wgt; a3 = __expf(v);
            ps0 += a0; ps1 += a1; ps2 += a2; ps3 += a3;
        }
        *(float4*)&lds_alpha[ln][sub][0] = make_float4(a0, a1, a2, a3);
        lds_src[ln][sub] = sid;

        float co[16];
        uint4 hv[16];
#pragma unroll
        for (int e = 0; e < 16; ++e) {
            co[e] = lds_alpha[ln][e][hd3];
            int s = lds_src[ln][e];
            hv[e] = *(const uint4*)&hbuf[(size_t)s * 128 + sub * 8];
        }
#pragma unroll
        for (int e = 0; e < 16; ++e) {
            ac0 = fmaf(co[e], __uint_as_float(hv[e].x << 16), ac0);
            ac1 = fmaf(co[e], __uint_as_float(hv[e].x & 0xffff0000u), ac1);
            ac2 = fmaf(co[e], __uint_as_float(hv[e].y << 16), ac2);
            ac3 = fmaf(co[e], __uint_as_float(hv[e].y & 0xffff0000u), ac3);
            ac4 = fmaf(co[e], __uint_as_float(hv[e].z << 16), ac4);
            ac5 = fmaf(co[e], __uint_as_float(hv[e].z & 0xffff0000u), ac5);
            ac6 = fmaf(co[e], __uint_as_float(hv[e].w << 16), ac6);
            ac7 = fmaf(co[e], __uint_as_float(hv[e].w & 0xffff0000u), ac7);
        }
    }
#pragma unroll
    for (int off = 1; off < 16; off <<= 1) {
        ps0 += __shfl_xor(ps0, off);
        ps1 += __shfl_xor(ps1, off);
        ps2 += __shfl_xor(ps2, off);
        ps3 += __shfl_xor(ps3, off);
    }
    float sv = (hd3 & 2) ? ((hd3 & 1) ? ps3 : ps2) : ((hd3 & 1) ? ps1 : ps0);
    float inv = 1.f / (sv + 1e-8f);
    float4 o0 = {ac0 * inv, ac1 * inv, ac2 * inv, ac3 * inv};
    float4 o1 = {ac4 * inv, ac5 * inv, ac6 * inv, ac7 * inv};
    *(float4*)&out[(size_t)n * 128 + sub * 8] = o0;
    *(float4*)&out[(size_t)n * 128 + sub * 8 + 4] = o1;
}

extern "C" void kernel_launch(void* const* d_in, const int* in_sizes, int n_in,
                              void* d_out, int out_size, void* d_ws, size_t ws_size,
                              hipStream_t stream)
{
    const float* x     = (const float*)d_in[0];
    const int*   ei    = (const int*)d_in[1];
    const float* ew    = (const float*)d_in[2];
    const float* W     = (const float*)d_in[3];
    const float* a_src = (const float*)d_in[4];
    const float* a_dst = (const float*)d_in[5];
    float* out = (float*)d_out;
    char* ws = (char*)d_ws;

    // workspace layout (byte offsets)
    unsigned short* hbuf = (unsigned short*)(ws);           // 25.6 MB bf16
    float* s_src = (float*)(ws + 25600000);                 // 1.6 MB
    float* s_dst = (float*)(ws + 27200000);                 // 1.6 MB
    int*   deg   = (int*)(ws + 28800000);                   // 400 KB
    int*   rowp  = (int*)(ws + 29200000);                   // 400 KB
    int*   gcur  = (int*)(ws + 29600000);                   // 2 KB (391 used)
    uint2* earr  = (uint2*)(ws + 29669632);                 // 12.8 MB
    uint2* ebin  = (uint2*)(ws + 42469632);                 // 16.0 MB

    proj_kernel<<<N_NODES / 32, 256, 0, stream>>>(x, W, a_src, a_dst,
                                                  hbuf, s_src, s_dst, gcur);
    binA_kernel<<<BINA_BLOCKS, 256, 0, stream>>>(ei, ew, gcur, ebin);
    binB_kernel<<<NBKT, 256, 0, stream>>>(ebin, gcur, earr, rowp, deg);
    gather_kernel<<<N_NODES / 16, 256, 0, stream>>>(earr, rowp, deg, s_src, s_dst,
                                                    hbuf, out);
}